// Round 13
// baseline (1259.021 us; speedup 1.0000x reference)
//
#include <hip/hip_runtime.h>
#include <hip/hip_bf16.h>

// WindowAttention (Swin) on MI355X — round 13
//   Base = R7 (best total, 1039us), upc=64 (R12 chunking hurt: +152us).
//   Change: k_cvt ELIMINATED — k_qkv_f stages A directly from fp32 x via
//   source-XOR-swizzled global_load_lds (fp32 tile in LDS, convert after
//   ds_read), saving 462MB of cvt traffic + one serial stage. B-chunk XOR
//   swizzle kills R7's 8-way B-read conflict. proj = R7 kernel verbatim;
//   attn = R12 (mask-fix) version.

typedef __attribute__((ext_vector_type(8))) short bf16x8;
typedef __attribute__((ext_vector_type(4))) float f32x4;

#define SEQ_N  49
#define CH     384
#define QKV_N  1152
#define UNIT_ROWS 3136   // 64 windows * 49 rows

__device__ __forceinline__ unsigned short f2b(float f) {
    union { float f; unsigned int u; } v; v.f = f;
    return (unsigned short)((v.u + 0x7FFFu + ((v.u >> 16) & 1u)) >> 16);
}

__device__ __forceinline__ bf16x8 ld8(const unsigned short* p) {
    return *(const bf16x8*)p;
}

__device__ __forceinline__ bf16x8 cvt8(float4 a, float4 b) {
    bf16x8 r;
    r[0] = (short)f2b(a.x); r[1] = (short)f2b(a.y);
    r[2] = (short)f2b(a.z); r[3] = (short)f2b(a.w);
    r[4] = (short)f2b(b.x); r[5] = (short)f2b(b.y);
    r[6] = (short)f2b(b.z); r[7] = (short)f2b(b.w);
    return r;
}

// async global->LDS, 16B/lane; lane i lands at lds_base + i*16 (HW-fixed)
__device__ __forceinline__ void gload16(const void* g, void* l) {
    __builtin_amdgcn_global_load_lds(
        (const __attribute__((address_space(1))) unsigned int*)g,
        (__attribute__((address_space(3))) unsigned int*)l, 16, 0, 0);
}

// bijective XCD-chunking swizzle (m204)
__device__ __forceinline__ int xcd_swizzle(int orig, int T) {
    int q = T >> 3, r = T & 7;
    int xcd = orig & 7, idx = orig >> 3;
    return (xcd < r ? xcd * (q + 1) : r * (q + 1) + (xcd - r) * q) + idx;
}

// ---------------- weight convert+transpose: Bt[n][k] = bf16(W[k][n]) --------
__global__ __launch_bounds__(256) void k_cvt_w(const float* __restrict__ wq,
        const float* __restrict__ wp, unsigned short* __restrict__ oq,
        unsigned short* __restrict__ op)
{
    int t = blockIdx.x * 256 + threadIdx.x;
    if (t < QKV_N * CH) {
        int n = t / CH, k = t - n * CH;
        oq[t] = f2b(wq[(size_t)k * QKV_N + n]);
    }
    if (t < CH * CH) {
        int n = t / CH, k = t - n * CH;
        op[t] = f2b(wp[(size_t)k * CH + n]);
    }
}

// ---------------- fused cvt+qkv GEMM: qkv[M][1152] = bf16(x fp32) @ Wq^T + b -
// x fp32 row-major [M][384]; Bt bf16 n-major [1152][384]. BM=BN=128, BK=32,
// 4 waves. A staged AS FP32 (16KB/buf) with chunk-XOR source swizzle; bf16
// conversion after ds_read. 3-buf depth-2 counted vmcnt(6), 1 barrier/tile.
__global__ __launch_bounds__(256) void k_qkv_f(
        const float* __restrict__ X,
        const unsigned short* __restrict__ Bt,
        const float* __restrict__ bias,
        unsigned short* __restrict__ C, int M, int mtiles)
{
    extern __shared__ unsigned short smem[];   // 3 bufs * 12288 ushorts (24KB)
    const int wg = xcd_swizzle(blockIdx.x, mtiles * 9);
    const int m0 = (wg / 9) * 128;
    const int n0 = (wg % 9) * 128;
    const int tid = threadIdx.x;
    const int lane = tid & 63, wv = tid >> 6;
    const int wm = (wv >> 1) * 64, wn = (wv & 1) * 64;
    const int l15 = lane & 15, g = lane >> 4;

    f32x4 acc[4][4];
#pragma unroll
    for (int a = 0; a < 4; ++a)
#pragma unroll
        for (int b = 0; b < 4; ++b) acc[a][b] = (f32x4){0.f, 0.f, 0.f, 0.f};

    // A staging: 4 gloads/wave, each 8 rows x 8 fp32-chunks(16B) = 1KB.
    // LDS pos p=(lane&7) holds logical chunk p^(row&7)  [row&7 == lane>>3]
    const float* aSrc[4]; int aLds[4];
#pragma unroll
    for (int i2 = 0; i2 < 4; ++i2) {
        int rloc = wv * 32 + i2 * 8 + (lane >> 3);
        int grow = m0 + rloc; if (grow > M - 1) grow = M - 1;
        aSrc[i2] = X + (size_t)grow * CH + (((lane & 7) ^ (lane >> 3)) * 4);
        aLds[i2] = (wv * 32 + i2 * 8) * 64;        // ushort offset (128B rows)
    }
    // B staging: 2 gloads/wave, each 16 rows x 4 bf16-chunks(16B) = 1KB.
    const unsigned short* bSrc[2]; int bLds[2];
#pragma unroll
    for (int j = 0; j < 2; ++j) {
        int rloc = wv * 32 + j * 16 + (lane >> 2);
        bSrc[j] = Bt + (size_t)(n0 + rloc) * CH + (((lane & 3) ^ ((lane >> 2) & 3)) * 8);
        bLds[j] = 8192 + (wv * 32 + j * 16) * 32;  // ushort offset (64B rows)
    }

#define STAGE(kc, b) do { unsigned short* pb = smem + (b) * 12288;  \
        gload16(aSrc[0] + (kc), pb + aLds[0]);                       \
        gload16(aSrc[1] + (kc), pb + aLds[1]);                       \
        gload16(aSrc[2] + (kc), pb + aLds[2]);                       \
        gload16(aSrc[3] + (kc), pb + aLds[3]);                       \
        gload16(bSrc[0] + (kc), pb + bLds[0]);                       \
        gload16(bSrc[1] + (kc), pb + bLds[1]); } while (0)

    const int ns = 12;                 // K=384, BK=32
    STAGE(0, 0);
    STAGE(32, 1);

    for (int t = 0; t < ns; ++t) {
        if (t + 1 < ns) asm volatile("s_waitcnt vmcnt(6)" ::: "memory");
        else            asm volatile("s_waitcnt vmcnt(0)" ::: "memory");
        __builtin_amdgcn_s_barrier();      // tile t staged; prev reads done
        __builtin_amdgcn_sched_barrier(0);
        if (t + 2 < ns) STAGE((t + 2) * 32, (t + 2) % 3);
        const unsigned short* pb = smem + (t % 3) * 12288;
        const float* pa = (const float*)pb;          // [128][32] fp32
        bf16x8 af[4], bfr[4];
#pragma unroll
        for (int mt = 0; mt < 4; ++mt) {
            int row = wm + mt * 16 + l15;
            int p0 = (2 * g) ^ (row & 7), p1 = (2 * g + 1) ^ (row & 7);
            float4 fa = *(const float4*)(pa + row * 32 + p0 * 4);
            float4 fb = *(const float4*)(pa + row * 32 + p1 * 4);
            af[mt] = cvt8(fa, fb);
        }
#pragma unroll
        for (int nt = 0; nt < 4; ++nt) {
            int row = wn + nt * 16 + l15;
            int p = g ^ (row & 3);
            bfr[nt] = ld8(pb + 8192 + row * 32 + p * 8);
        }
        __builtin_amdgcn_s_setprio(1);
#pragma unroll
        for (int mt = 0; mt < 4; ++mt)
#pragma unroll
            for (int nt = 0; nt < 4; ++nt)
                acc[mt][nt] = __builtin_amdgcn_mfma_f32_16x16x32_bf16(
                        af[mt], bfr[nt], acc[mt][nt], 0, 0, 0);
        __builtin_amdgcn_s_setprio(0);
    }
#undef STAGE

#pragma unroll
    for (int mt = 0; mt < 4; ++mt)
#pragma unroll
        for (int nt = 0; nt < 4; ++nt) {
            int col = n0 + wn + nt * 16 + l15;
            float bb = bias[col];
#pragma unroll
            for (int r = 0; r < 4; ++r) {
                int row = m0 + wm + mt * 16 + g * 4 + r;
                if (row < M)
                    C[(size_t)row * QKV_N + col] = f2b(acc[mt][nt][r] + bb);
            }
        }
}

// ---------------- R7 GEMM (verbatim): C[M][ldc] = A @ Bt^T + bias ------------
// A bf16 row-major [M][lda], Bt bf16 n-major [N][K]. 128x128 tile, BK=32,
// 3-buffer LDS, depth-2 prefetch, counted vmcnt.
template<int OUTF32>
__global__ __launch_bounds__(256) void k_gemm(
        const unsigned short* __restrict__ A, int lda,
        const unsigned short* __restrict__ Bt, int K,
        const float* __restrict__ bias,
        unsigned short* __restrict__ Cb, float* __restrict__ Cf, int ldc,
        int M, int ntiles, int mtiles)
{
    __shared__ unsigned short As[3 * 4096];
    __shared__ unsigned short Bs[3 * 4096];
    const int wg = xcd_swizzle(blockIdx.x, mtiles * ntiles);
    const int m0 = (wg / ntiles) * 128;
    const int n0 = (wg % ntiles) * 128;
    const int tid = threadIdx.x;
    const int lane = tid & 63, wid = tid >> 6;
    const int wm = (wid >> 1) * 64, wn = (wid & 1) * 64;
    const int l15 = lane & 15, g = lane >> 4;

    f32x4 acc[4][4];
#pragma unroll
    for (int a = 0; a < 4; ++a)
#pragma unroll
        for (int b = 0; b < 4; ++b) acc[a][b] = (f32x4){0.f, 0.f, 0.f, 0.f};

    const int r0 = wid * 16 + (lane >> 2);
    const int kofs = (lane & 3) * 8;
    int ra0 = m0 + r0;       if (ra0 > M - 1) ra0 = M - 1;
    int ra1 = m0 + 64 + r0;  if (ra1 > M - 1) ra1 = M - 1;
    const unsigned short* a0p = A + (size_t)ra0 * lda + kofs;
    const unsigned short* a1p = A + (size_t)ra1 * lda + kofs;
    const unsigned short* b0p = Bt + (size_t)(n0 + r0) * K + kofs;
    const unsigned short* b1p = Bt + (size_t)(n0 + 64 + r0) * K + kofs;
    const int lo = wid * 512;

#define STAGE(kt, buf) do {                                   \
        gload16(a0p + (kt), &As[(buf) * 4096 + lo]);          \
        gload16(a1p + (kt), &As[(buf) * 4096 + 2048 + lo]);   \
        gload16(b0p + (kt), &Bs[(buf) * 4096 + lo]);          \
        gload16(b1p + (kt), &Bs[(buf) * 4096 + 2048 + lo]);   \
    } while (0)

#define COMPUTE(buf) do {                                                     \
        bf16x8 af[4], bfr[4];                                                 \
        _Pragma("unroll")                                                     \
        for (int mt = 0; mt < 4; ++mt)                                        \
            af[mt] = ld8(&As[(buf) * 4096 + (wm + mt * 16 + l15) * 32 + g * 8]); \
        _Pragma("unroll")                                                     \
        for (int nt = 0; nt < 4; ++nt)                                        \
            bfr[nt] = ld8(&Bs[(buf) * 4096 + (wn + nt * 16 + l15) * 32 + g * 8]); \
        _Pragma("unroll")                                                     \
        for (int mt = 0; mt < 4; ++mt)                                        \
            _Pragma("unroll")                                                 \
            for (int nt = 0; nt < 4; ++nt)                                    \
                acc[mt][nt] = __builtin_amdgcn_mfma_f32_16x16x32_bf16(        \
                        af[mt], bfr[nt], acc[mt][nt], 0, 0, 0);               \
    } while (0)

    const int nsteps = K >> 5;

    STAGE(0, 0);
    STAGE(32, 1);

    int cur = 0;
    for (int t = 0; t < nsteps - 2; ++t) {
        int pf = cur + 2; if (pf >= 3) pf -= 3;
        STAGE((t + 2) * 32, pf);
        __builtin_amdgcn_sched_barrier(0);
        asm volatile("s_waitcnt vmcnt(8)" ::: "memory");
        __builtin_amdgcn_sched_barrier(0);
        __builtin_amdgcn_s_barrier();
        __builtin_amdgcn_sched_barrier(0);
        COMPUTE(cur);
        __builtin_amdgcn_sched_barrier(0);
        __builtin_amdgcn_s_barrier();
        __builtin_amdgcn_sched_barrier(0);
        cur = (cur == 2) ? 0 : cur + 1;
    }
    asm volatile("s_waitcnt vmcnt(4)" ::: "memory");
    __builtin_amdgcn_sched_barrier(0);
    __builtin_amdgcn_s_barrier();
    __builtin_amdgcn_sched_barrier(0);
    COMPUTE(cur);
    cur = (cur == 2) ? 0 : cur + 1;
    asm volatile("s_waitcnt vmcnt(0)" ::: "memory");
    __builtin_amdgcn_sched_barrier(0);
    __builtin_amdgcn_s_barrier();
    __builtin_amdgcn_sched_barrier(0);
    COMPUTE(cur);
#undef STAGE
#undef COMPUTE

#pragma unroll
    for (int mt = 0; mt < 4; ++mt)
#pragma unroll
        for (int nt = 0; nt < 4; ++nt) {
            int col = n0 + wn + nt * 16 + l15;
            float bb = bias[col];
#pragma unroll
            for (int r = 0; r < 4; ++r) {
                int row = m0 + wm + mt * 16 + g * 4 + r;
                if (row < M) {
                    if (OUTF32)
                        Cf[(size_t)row * ldc + col] = acc[mt][nt][r] + bb;
                    else
                        Cb[(size_t)row * ldc + col] = f2b(acc[mt][nt][r] + bb);
                }
            }
        }
}

// ---------------- attention: 1 wave per (window, head) -----------------------
// chunks start at multiples of 64 windows; mask repeats every 64 -> wimg local.
__global__ __launch_bounds__(256) void k_attn(unsigned short* __restrict__ qkv,
        const float* __restrict__ mask, const float* __restrict__ btab)
{
    extern __shared__ unsigned short sm[];
    const int tid = threadIdx.x;
    const int lane = tid & 63, wv = tid >> 6;
    const int l15 = lane & 15, g = lane >> 4;
    const int pair = blockIdx.x * 4 + wv;
    const int winloc = pair / 12;
    const int h = pair - winloc * 12;
    const int wimg = winloc & 63;
    const int co = h * 32;
    unsigned short* Vt = sm + wv * 6912;     // [32][72]  V^T
    unsigned short* Pw = Vt + 32 * 72;       // [64][72]  P
    unsigned short* src = qkv + (size_t)winloc * SEQ_N * QKV_N;

    for (int t = lane; t < 32 * 16; t += 64) {
        int c = t >> 4, kk = 48 + (t & 15);
        Vt[c * 72 + kk] = 0;
    }
    for (int t = lane; t < 49 * 4; t += 64) {
        int row = t >> 2, cb = (t & 3) * 8;
        const unsigned short* vp = src + (size_t)row * QKV_N + 768 + co + cb;
        ushort4 a = ((const ushort4*)vp)[0];
        ushort4 b = ((const ushort4*)vp)[1];
        Vt[(cb + 0) * 72 + row] = a.x; Vt[(cb + 1) * 72 + row] = a.y;
        Vt[(cb + 2) * 72 + row] = a.z; Vt[(cb + 3) * 72 + row] = a.w;
        Vt[(cb + 4) * 72 + row] = b.x; Vt[(cb + 5) * 72 + row] = b.y;
        Vt[(cb + 6) * 72 + row] = b.z; Vt[(cb + 7) * 72 + row] = b.w;
    }

    bf16x8 qf[4], kf[4];
#pragma unroll
    for (int mt = 0; mt < 4; ++mt) {
        int r = mt * 16 + l15; if (r > 48) r = 48;
        qf[mt] = ld8(src + (size_t)r * QKV_N + co + g * 8);
    }
#pragma unroll
    for (int nt = 0; nt < 4; ++nt) {
        int r = nt * 16 + l15; if (r > 48) r = 48;
        kf[nt] = ld8(src + (size_t)r * QKV_N + CH + co + g * 8);
    }

    f32x4 sa[4][4];
#pragma unroll
    for (int mt = 0; mt < 4; ++mt)
#pragma unroll
        for (int nt = 0; nt < 4; ++nt) sa[mt][nt] = (f32x4){0.f, 0.f, 0.f, 0.f};
#pragma unroll
    for (int mt = 0; mt < 4; ++mt)
#pragma unroll
        for (int nt = 0; nt < 4; ++nt)
            sa[mt][nt] = __builtin_amdgcn_mfma_f32_16x16x32_bf16(
                    qf[mt], kf[nt], sa[mt][nt], 0, 0, 0);

    int jj[4], jh[4], jw4[4];
#pragma unroll
    for (int nt = 0; nt < 4; ++nt) {
        int j = nt * 16 + l15;
        jj[nt] = j; jh[nt] = j / 7; jw4[nt] = j - (j / 7) * 7;
    }
    const float scale = 0.17677669529663687f;
#pragma unroll
    for (int mt = 0; mt < 4; ++mt) {
#pragma unroll
        for (int r = 0; r < 4; ++r) {
            int i = mt * 16 + g * 4 + r;
            int ic = i < 49 ? i : 48;
            int ih = ic / 7, iw = ic - (ic / 7) * 7;
            const float* mrow = mask + (size_t)wimg * 2401 + ic * 49;
            float sv[4];
#pragma unroll
            for (int nt = 0; nt < 4; ++nt) {
                float s = sa[mt][nt][r];
                if (jj[nt] < 49) {
                    int idx = (ih - jh[nt] + 6) * 13 + (iw - jw4[nt] + 6);
                    s = s * scale + btab[idx * 12 + h] + mrow[jj[nt]];
                } else s = -1e30f;
                sv[nt] = s;
            }
            float mx = fmaxf(fmaxf(sv[0], sv[1]), fmaxf(sv[2], sv[3]));
#pragma unroll
            for (int d = 1; d < 16; d <<= 1) mx = fmaxf(mx, __shfl_xor(mx, d));
            float sum = 0.f;
#pragma unroll
            for (int nt = 0; nt < 4; ++nt) { sv[nt] = __expf(sv[nt] - mx); sum += sv[nt]; }
#pragma unroll
            for (int d = 1; d < 16; d <<= 1) sum += __shfl_xor(sum, d);
            float inv = 1.0f / sum;
#pragma unroll
            for (int nt = 0; nt < 4; ++nt)
                Pw[i * 72 + nt * 16 + l15] = f2b(sv[nt] * inv);
        }
    }
    __syncthreads();

    f32x4 oa[4][2];
#pragma unroll
    for (int mt = 0; mt < 4; ++mt)
#pragma unroll
        for (int nt = 0; nt < 2; ++nt) oa[mt][nt] = (f32x4){0.f, 0.f, 0.f, 0.f};
#pragma unroll
    for (int ks = 0; ks < 2; ++ks) {
        bf16x8 pf[4];
#pragma unroll
        for (int mt = 0; mt < 4; ++mt)
            pf[mt] = ld8(Pw + (mt * 16 + l15) * 72 + ks * 32 + g * 8);
#pragma unroll
        for (int nt = 0; nt < 2; ++nt) {
            bf16x8 vf = ld8(Vt + (nt * 16 + l15) * 72 + ks * 32 + g * 8);
#pragma unroll
            for (int mt = 0; mt < 4; ++mt)
                oa[mt][nt] = __builtin_amdgcn_mfma_f32_16x16x32_bf16(
                        pf[mt], vf, oa[mt][nt], 0, 0, 0);
        }
    }

#pragma unroll
    for (int mt = 0; mt < 4; ++mt)
#pragma unroll
        for (int r = 0; r < 4; ++r) {
            int i = mt * 16 + g * 4 + r;
            if (i < 49) {
#pragma unroll
                for (int nt = 0; nt < 2; ++nt)
                    src[(size_t)i * QKV_N + co + nt * 16 + l15] = f2b(oa[mt][nt][r]);
            }
        }
}

extern "C" void kernel_launch(void* const* d_in, const int* in_sizes, int n_in,
                              void* d_out, int out_size, void* d_ws, size_t ws_size,
                              hipStream_t stream) {
    const float* x      = (const float*)d_in[0];
    const float* mask   = (const float*)d_in[1];
    const float* qkv_w  = (const float*)d_in[2];
    const float* qkv_b  = (const float*)d_in[3];
    const float* proj_w = (const float*)d_in[4];
    const float* proj_b = (const float*)d_in[5];
    const float* btab   = (const float*)d_in[6];
    float* out = (float*)d_out;

    unsigned short* wq_bt = (unsigned short*)d_ws;
    unsigned short* wp_bt = wq_bt + QKV_N * CH;
    unsigned short* qkv   = wp_bt + CH * CH;
    const size_t fixed = (size_t)(QKV_N * CH + CH * CH) * 2;
    const size_t unit  = (size_t)UNIT_ROWS * QKV_N * 2;   // 7,225,344 B
    if (ws_size < fixed + unit) return;
    int upc = (int)((ws_size - fixed) / unit);
    if (upc > 64) upc = 64;

    const int smem2 = 4 * 6912 * 2;   // 55,296 B (attn)
    hipFuncSetAttribute(reinterpret_cast<const void*>(k_attn),
                        hipFuncAttributeMaxDynamicSharedMemorySize, smem2);
    const int smemQ = 3 * 12288 * 2;  // 73,728 B (fused qkv)
    hipFuncSetAttribute(reinterpret_cast<const void*>(k_qkv_f),
                        hipFuncAttributeMaxDynamicSharedMemorySize, smemQ);

    dim3 blk(256);
    k_cvt_w<<<dim3((QKV_N * CH + 255) / 256), blk, 0, stream>>>(qkv_w, proj_w, wq_bt, wp_bt);

    for (int u0 = 0; u0 < 64; u0 += upc) {
        int units = (64 - u0) < upc ? (64 - u0) : upc;
        int m_base = u0 * UNIT_ROWS;
        int Mc = units * UNIT_ROWS;
        int mtiles = (Mc + 127) / 128;
        k_qkv_f<<<dim3(mtiles * 9), blk, smemQ, stream>>>(
                x + (size_t)m_base * CH, wq_bt, qkv_b, qkv, Mc, mtiles);
        k_attn<<<dim3(units * 192), blk, smem2, stream>>>(qkv, mask, btab);
        k_gemm<1><<<dim3(mtiles * 3), blk, 0, stream>>>(
                qkv, QKV_N, wp_bt, CH, proj_b, nullptr, out + (size_t)m_base * CH,
                CH, Mc, 3, mtiles);
    }
}

// Round 14
// 937.556 us; speedup vs baseline: 1.3429x; 1.3429x over previous
//
#include <hip/hip_runtime.h>
#include <hip/hip_bf16.h>

// WindowAttention (Swin) on MI355X — round 14
//   Base = R7 (best total 1039us; qkv GEMM verbatim), mask-fix semantics.
//   Changes (attn only — now understood to be ~400us, the 2nd whale):
//   1) k_bm: precompute fused rel-pos-bias + shift-mask table
//      bm[64][12][49][49] fp32 (7.4MB, L3-resident) — removes per-lane
//      scalar btab gathers + mask loads + idx math from softmax inner loop.
//   2) Pw shrunk 64->52 rows (clamped pad reads): 48.4KB/block -> 3 blk/CU
//      (8->12 waves/CU).

typedef __attribute__((ext_vector_type(8))) short bf16x8;
typedef __attribute__((ext_vector_type(4))) float f32x4;

#define SEQ_N  49
#define CH     384
#define QKV_N  1152
#define UNIT_ROWS 3136   // 64 windows * 49 rows
#define BM_ELEMS (64 * 12 * 49 * 49)   // 1,845,312

__device__ __forceinline__ unsigned short f2b(float f) {
    union { float f; unsigned int u; } v; v.f = f;
    return (unsigned short)((v.u + 0x7FFFu + ((v.u >> 16) & 1u)) >> 16);
}

__device__ __forceinline__ bf16x8 ld8(const unsigned short* p) {
    return *(const bf16x8*)p;
}

// async global->LDS, 16B/lane; lds dst is wave-uniform base + lane*16
__device__ __forceinline__ void gload16(const unsigned short* g, unsigned short* l) {
    __builtin_amdgcn_global_load_lds(
        (const __attribute__((address_space(1))) unsigned int*)g,
        (__attribute__((address_space(3))) unsigned int*)l, 16, 0, 0);
}

// bijective XCD-chunking swizzle (m204)
__device__ __forceinline__ int xcd_swizzle(int orig, int T) {
    int q = T >> 3, r = T & 7;
    int xcd = orig & 7, idx = orig >> 3;
    return (xcd < r ? xcd * (q + 1) : r * (q + 1) + (xcd - r) * q) + idx;
}

// ---------------- weight convert+transpose: Bt[n][k] = bf16(W[k][n]) --------
__global__ __launch_bounds__(256) void k_cvt_w(const float* __restrict__ wq,
        const float* __restrict__ wp, unsigned short* __restrict__ oq,
        unsigned short* __restrict__ op)
{
    int t = blockIdx.x * 256 + threadIdx.x;
    if (t < QKV_N * CH) {
        int n = t / CH, k = t - n * CH;
        oq[t] = f2b(wq[(size_t)k * QKV_N + n]);
    }
    if (t < CH * CH) {
        int n = t / CH, k = t - n * CH;
        op[t] = f2b(wp[(size_t)k * CH + n]);
    }
}

// ---------------- fused bias+mask table: bm[w][h][i][j] ----------------------
__global__ __launch_bounds__(256) void k_bm(const float* __restrict__ btab,
        const float* __restrict__ mask, float* __restrict__ bm)
{
    int t = blockIdx.x * 256 + threadIdx.x;
    if (t >= BM_ELEMS) return;
    int w   = t / (12 * 2401);
    int rem = t - w * 12 * 2401;
    int h   = rem / 2401;
    int ij  = rem - h * 2401;
    int i = ij / 49, j = ij - (ij / 49) * 49;
    int ih = i / 7, iw = i - (i / 7) * 7;
    int jh = j / 7, jw = j - (j / 7) * 7;
    int idx = (ih - jh + 6) * 13 + (iw - jw + 6);
    bm[t] = btab[idx * 12 + h] + mask[(size_t)w * 2401 + ij];
}

// ---------------- x fp32 -> bf16 (vectorized, grid-stride) -------------------
__global__ __launch_bounds__(256) void k_cvt(const float* __restrict__ in,
        unsigned short* __restrict__ outp, int n8)
{
    int stride = gridDim.x * 256;
    for (int i = blockIdx.x * 256 + threadIdx.x; i < n8; i += stride) {
        const float4* p = (const float4*)(in + (size_t)i * 8);
        float4 a = p[0], b = p[1];
        uint4 v;
        v.x = (unsigned)f2b(a.x) | ((unsigned)f2b(a.y) << 16);
        v.y = (unsigned)f2b(a.z) | ((unsigned)f2b(a.w) << 16);
        v.z = (unsigned)f2b(b.x) | ((unsigned)f2b(b.y) << 16);
        v.w = (unsigned)f2b(b.z) | ((unsigned)f2b(b.w) << 16);
        *(uint4*)(outp + (size_t)i * 8) = v;
    }
}

// ---------------- R7 GEMM (verbatim): C[M][ldc] = A @ Bt^T + bias ------------
template<int OUTF32>
__global__ __launch_bounds__(256) void k_gemm(
        const unsigned short* __restrict__ A, int lda,
        const unsigned short* __restrict__ Bt, int K,
        const float* __restrict__ bias,
        unsigned short* __restrict__ Cb, float* __restrict__ Cf, int ldc,
        int M, int ntiles, int mtiles)
{
    __shared__ unsigned short As[3 * 4096];
    __shared__ unsigned short Bs[3 * 4096];
    const int wg = xcd_swizzle(blockIdx.x, mtiles * ntiles);
    const int m0 = (wg / ntiles) * 128;
    const int n0 = (wg % ntiles) * 128;
    const int tid = threadIdx.x;
    const int lane = tid & 63, wid = tid >> 6;
    const int wm = (wid >> 1) * 64, wn = (wid & 1) * 64;
    const int l15 = lane & 15, g = lane >> 4;

    f32x4 acc[4][4];
#pragma unroll
    for (int a = 0; a < 4; ++a)
#pragma unroll
        for (int b = 0; b < 4; ++b) acc[a][b] = (f32x4){0.f, 0.f, 0.f, 0.f};

    const int r0 = wid * 16 + (lane >> 2);
    const int kofs = (lane & 3) * 8;
    int ra0 = m0 + r0;       if (ra0 > M - 1) ra0 = M - 1;
    int ra1 = m0 + 64 + r0;  if (ra1 > M - 1) ra1 = M - 1;
    const unsigned short* a0p = A + (size_t)ra0 * lda + kofs;
    const unsigned short* a1p = A + (size_t)ra1 * lda + kofs;
    const unsigned short* b0p = Bt + (size_t)(n0 + r0) * K + kofs;
    const unsigned short* b1p = Bt + (size_t)(n0 + 64 + r0) * K + kofs;
    const int lo = wid * 512;

#define STAGE(kt, buf) do {                                   \
        gload16(a0p + (kt), &As[(buf) * 4096 + lo]);          \
        gload16(a1p + (kt), &As[(buf) * 4096 + 2048 + lo]);   \
        gload16(b0p + (kt), &Bs[(buf) * 4096 + lo]);          \
        gload16(b1p + (kt), &Bs[(buf) * 4096 + 2048 + lo]);   \
    } while (0)

#define COMPUTE(buf) do {                                                     \
        bf16x8 af[4], bfr[4];                                                 \
        _Pragma("unroll")                                                     \
        for (int mt = 0; mt < 4; ++mt)                                        \
            af[mt] = ld8(&As[(buf) * 4096 + (wm + mt * 16 + l15) * 32 + g * 8]); \
        _Pragma("unroll")                                                     \
        for (int nt = 0; nt < 4; ++nt)                                        \
            bfr[nt] = ld8(&Bs[(buf) * 4096 + (wn + nt * 16 + l15) * 32 + g * 8]); \
        _Pragma("unroll")                                                     \
        for (int mt = 0; mt < 4; ++mt)                                        \
            _Pragma("unroll")                                                 \
            for (int nt = 0; nt < 4; ++nt)                                    \
                acc[mt][nt] = __builtin_amdgcn_mfma_f32_16x16x32_bf16(        \
                        af[mt], bfr[nt], acc[mt][nt], 0, 0, 0);               \
    } while (0)

    const int nsteps = K >> 5;

    STAGE(0, 0);
    STAGE(32, 1);

    int cur = 0;
    for (int t = 0; t < nsteps - 2; ++t) {
        int pf = cur + 2; if (pf >= 3) pf -= 3;
        STAGE((t + 2) * 32, pf);
        __builtin_amdgcn_sched_barrier(0);
        asm volatile("s_waitcnt vmcnt(8)" ::: "memory");
        __builtin_amdgcn_sched_barrier(0);
        __builtin_amdgcn_s_barrier();
        __builtin_amdgcn_sched_barrier(0);
        COMPUTE(cur);
        __builtin_amdgcn_sched_barrier(0);
        __builtin_amdgcn_s_barrier();
        __builtin_amdgcn_sched_barrier(0);
        cur = (cur == 2) ? 0 : cur + 1;
    }
    asm volatile("s_waitcnt vmcnt(4)" ::: "memory");
    __builtin_amdgcn_sched_barrier(0);
    __builtin_amdgcn_s_barrier();
    __builtin_amdgcn_sched_barrier(0);
    COMPUTE(cur);
    cur = (cur == 2) ? 0 : cur + 1;
    asm volatile("s_waitcnt vmcnt(0)" ::: "memory");
    __builtin_amdgcn_sched_barrier(0);
    __builtin_amdgcn_s_barrier();
    __builtin_amdgcn_sched_barrier(0);
    COMPUTE(cur);
#undef STAGE
#undef COMPUTE

#pragma unroll
    for (int mt = 0; mt < 4; ++mt)
#pragma unroll
        for (int nt = 0; nt < 4; ++nt) {
            int col = n0 + wn + nt * 16 + l15;
            float bb = bias[col];
#pragma unroll
            for (int r = 0; r < 4; ++r) {
                int row = m0 + wm + mt * 16 + g * 4 + r;
                if (row < M) {
                    if (OUTF32)
                        Cf[(size_t)row * ldc + col] = acc[mt][nt][r] + bb;
                    else
                        Cb[(size_t)row * ldc + col] = f2b(acc[mt][nt][r] + bb);
                }
            }
        }
}

// ---------------- attention: 1 wave per (window, head) -----------------------
// Per-wave LDS: Vt [32][72] + Pw [52][72] = 12,096 B -> 48,384 B/block
// -> 3 blocks/CU. Fused bias+mask from bm table.
__global__ __launch_bounds__(256) void k_attn(unsigned short* __restrict__ qkv,
        const float* __restrict__ bm)
{
    extern __shared__ unsigned short sm[];
    const int tid = threadIdx.x;
    const int lane = tid & 63, wv = tid >> 6;
    const int l15 = lane & 15, g = lane >> 4;
    const int pair = blockIdx.x * 4 + wv;
    const int winloc = pair / 12;
    const int h = pair - winloc * 12;
    const int wimg = winloc & 63;
    const int co = h * 32;
    unsigned short* Vt = sm + wv * 6048;     // [32][72]  V^T
    unsigned short* Pw = Vt + 32 * 72;       // [52][72]  P
    unsigned short* src = qkv + (size_t)winloc * SEQ_N * QKV_N;
    const float* bmh = bm + ((size_t)(wimg * 12 + h)) * 2401;

    for (int t = lane; t < 32 * 16; t += 64) {
        int c = t >> 4, kk = 48 + (t & 15);
        Vt[c * 72 + kk] = 0;
    }
    for (int t = lane; t < 49 * 4; t += 64) {
        int row = t >> 2, cb = (t & 3) * 8;
        const unsigned short* vp = src + (size_t)row * QKV_N + 768 + co + cb;
        ushort4 a = ((const ushort4*)vp)[0];
        ushort4 b = ((const ushort4*)vp)[1];
        Vt[(cb + 0) * 72 + row] = a.x; Vt[(cb + 1) * 72 + row] = a.y;
        Vt[(cb + 2) * 72 + row] = a.z; Vt[(cb + 3) * 72 + row] = a.w;
        Vt[(cb + 4) * 72 + row] = b.x; Vt[(cb + 5) * 72 + row] = b.y;
        Vt[(cb + 6) * 72 + row] = b.z; Vt[(cb + 7) * 72 + row] = b.w;
    }

    bf16x8 qf[4], kf[4];
#pragma unroll
    for (int mt = 0; mt < 4; ++mt) {
        int r = mt * 16 + l15; if (r > 48) r = 48;
        qf[mt] = ld8(src + (size_t)r * QKV_N + co + g * 8);
    }
#pragma unroll
    for (int nt = 0; nt < 4; ++nt) {
        int r = nt * 16 + l15; if (r > 48) r = 48;
        kf[nt] = ld8(src + (size_t)r * QKV_N + CH + co + g * 8);
    }

    f32x4 sa[4][4];
#pragma unroll
    for (int mt = 0; mt < 4; ++mt)
#pragma unroll
        for (int nt = 0; nt < 4; ++nt) sa[mt][nt] = (f32x4){0.f, 0.f, 0.f, 0.f};
#pragma unroll
    for (int mt = 0; mt < 4; ++mt)
#pragma unroll
        for (int nt = 0; nt < 4; ++nt)
            sa[mt][nt] = __builtin_amdgcn_mfma_f32_16x16x32_bf16(
                    qf[mt], kf[nt], sa[mt][nt], 0, 0, 0);

    int jj[4];
#pragma unroll
    for (int nt = 0; nt < 4; ++nt) jj[nt] = nt * 16 + l15;
    const float scale = 0.17677669529663687f;
#pragma unroll
    for (int mt = 0; mt < 4; ++mt) {
#pragma unroll
        for (int r = 0; r < 4; ++r) {
            int i = mt * 16 + g * 4 + r;
            int ic = i < 49 ? i : 48;
            const float* bmrow = bmh + ic * 49;
            float sv[4];
#pragma unroll
            for (int nt = 0; nt < 4; ++nt) {
                float s = sa[mt][nt][r];
                sv[nt] = (jj[nt] < 49) ? (s * scale + bmrow[jj[nt]]) : -1e30f;
            }
            float mx = fmaxf(fmaxf(sv[0], sv[1]), fmaxf(sv[2], sv[3]));
#pragma unroll
            for (int d = 1; d < 16; d <<= 1) mx = fmaxf(mx, __shfl_xor(mx, d));
            float sum = 0.f;
#pragma unroll
            for (int nt = 0; nt < 4; ++nt) { sv[nt] = __expf(sv[nt] - mx); sum += sv[nt]; }
#pragma unroll
            for (int d = 1; d < 16; d <<= 1) sum += __shfl_xor(sum, d);
            float inv = 1.0f / sum;
            if (i < 52) {
#pragma unroll
                for (int nt = 0; nt < 4; ++nt)
                    Pw[i * 72 + nt * 16 + l15] = f2b(sv[nt] * inv);
            }
        }
    }
    __syncthreads();

    f32x4 oa[4][2];
#pragma unroll
    for (int mt = 0; mt < 4; ++mt)
#pragma unroll
        for (int nt = 0; nt < 2; ++nt) oa[mt][nt] = (f32x4){0.f, 0.f, 0.f, 0.f};
#pragma unroll
    for (int ks = 0; ks < 2; ++ks) {
        bf16x8 pf[4];
#pragma unroll
        for (int mt = 0; mt < 4; ++mt) {
            int pr = mt * 16 + l15; if (pr > 51) pr = 51;   // pad rows discarded
            pf[mt] = ld8(Pw + pr * 72 + ks * 32 + g * 8);
        }
#pragma unroll
        for (int nt = 0; nt < 2; ++nt) {
            bf16x8 vf = ld8(Vt + (nt * 16 + l15) * 72 + ks * 32 + g * 8);
#pragma unroll
            for (int mt = 0; mt < 4; ++mt)
                oa[mt][nt] = __builtin_amdgcn_mfma_f32_16x16x32_bf16(
                        pf[mt], vf, oa[mt][nt], 0, 0, 0);
        }
    }

#pragma unroll
    for (int mt = 0; mt < 4; ++mt)
#pragma unroll
        for (int r = 0; r < 4; ++r) {
            int i = mt * 16 + g * 4 + r;
            if (i < 49) {
#pragma unroll
                for (int nt = 0; nt < 2; ++nt)
                    src[(size_t)i * QKV_N + co + nt * 16 + l15] = f2b(oa[mt][nt][r]);
            }
        }
}

extern "C" void kernel_launch(void* const* d_in, const int* in_sizes, int n_in,
                              void* d_out, int out_size, void* d_ws, size_t ws_size,
                              hipStream_t stream) {
    const float* x      = (const float*)d_in[0];
    const float* mask   = (const float*)d_in[1];
    const float* qkv_w  = (const float*)d_in[2];
    const float* qkv_b  = (const float*)d_in[3];
    const float* proj_w = (const float*)d_in[4];
    const float* proj_b = (const float*)d_in[5];
    const float* btab   = (const float*)d_in[6];
    float* out = (float*)d_out;

    unsigned short* wq_bt = (unsigned short*)d_ws;
    unsigned short* wp_bt = wq_bt + QKV_N * CH;
    float*          bm    = (float*)(wp_bt + CH * CH);
    unsigned short* base  = (unsigned short*)(bm + BM_ELEMS);
    const size_t fixed = (size_t)(QKV_N * CH + CH * CH) * 2 + (size_t)BM_ELEMS * 4;
    const size_t unit  = (size_t)UNIT_ROWS * (CH + QKV_N) * 2;
    if (ws_size < fixed + unit) return;
    int upc = (int)((ws_size - fixed) / unit);
    if (upc > 64) upc = 64;
    unsigned short* xb  = base;
    unsigned short* qkv = base + (size_t)upc * UNIT_ROWS * CH;

    const int smem2 = 4 * 6048 * 2;   // 48,384 B -> 3 blocks/CU (attn)
    hipFuncSetAttribute(reinterpret_cast<const void*>(k_attn),
                        hipFuncAttributeMaxDynamicSharedMemorySize, smem2);

    dim3 blk(256);
    k_cvt_w<<<dim3((QKV_N * CH + 255) / 256), blk, 0, stream>>>(qkv_w, proj_w, wq_bt, wp_bt);
    k_bm   <<<dim3((BM_ELEMS + 255) / 256), blk, 0, stream>>>(btab, mask, bm);

    for (int u0 = 0; u0 < 64; u0 += upc) {
        int units = (64 - u0) < upc ? (64 - u0) : upc;
        int m_base = u0 * UNIT_ROWS;
        int Mc = units * UNIT_ROWS;
        int mtiles = (Mc + 127) / 128;
        k_cvt<<<dim3(2048), blk, 0, stream>>>(x + (size_t)m_base * CH, xb, Mc * 48);
        k_gemm<0><<<dim3(mtiles * 9), blk, 0, stream>>>(
                xb, CH, wq_bt, CH, qkv_b, qkv, nullptr, QKV_N, Mc, 9, mtiles);
        k_attn<<<dim3(units * 192), blk, smem2, stream>>>(qkv, bm);
        k_gemm<1><<<dim3(mtiles * 3), blk, 0, stream>>>(
                qkv, QKV_N, wp_bt, CH, proj_b, nullptr, out + (size_t)m_base * CH,
                CH, Mc, 3, mtiles);
    }
}

// Round 15
// 917.982 us; speedup vs baseline: 1.3715x; 1.0213x over previous
//
#include <hip/hip_runtime.h>
#include <hip/hip_bf16.h>

// WindowAttention (Swin) on MI355X — round 15
//   Base = R14 (938us). Change: k_gemm goes 256->512 threads, 8 waves of
//   64x32 (acc 32 AGPR/thread instead of 64). Diagnosis: 4x4-acc decomposition
//   register-caps occupancy at 3 waves/SIMD (68 VGPR + 64 AGPR unified) ->
//   every R3-R10 schedule hit the same latency*concurrency wall (staging at
//   20% of L2 BW). 8-wave/32-acc + __launch_bounds__(512,6) doubles resident
//   waves (6/SIMD). Same 3-buf counted-vmcnt pipeline, same LDS layout.
//   attn/cvt/bm = R14 verbatim.

typedef __attribute__((ext_vector_type(8))) short bf16x8;
typedef __attribute__((ext_vector_type(4))) float f32x4;

#define SEQ_N  49
#define CH     384
#define QKV_N  1152
#define UNIT_ROWS 3136   // 64 windows * 49 rows
#define BM_ELEMS (64 * 12 * 49 * 49)   // 1,845,312

__device__ __forceinline__ unsigned short f2b(float f) {
    union { float f; unsigned int u; } v; v.f = f;
    return (unsigned short)((v.u + 0x7FFFu + ((v.u >> 16) & 1u)) >> 16);
}

__device__ __forceinline__ bf16x8 ld8(const unsigned short* p) {
    return *(const bf16x8*)p;
}

// async global->LDS, 16B/lane; lds dst is wave-uniform base + lane*16
__device__ __forceinline__ void gload16(const unsigned short* g, unsigned short* l) {
    __builtin_amdgcn_global_load_lds(
        (const __attribute__((address_space(1))) unsigned int*)g,
        (__attribute__((address_space(3))) unsigned int*)l, 16, 0, 0);
}

// bijective XCD-chunking swizzle (m204)
__device__ __forceinline__ int xcd_swizzle(int orig, int T) {
    int q = T >> 3, r = T & 7;
    int xcd = orig & 7, idx = orig >> 3;
    return (xcd < r ? xcd * (q + 1) : r * (q + 1) + (xcd - r) * q) + idx;
}

// ---------------- weight convert+transpose: Bt[n][k] = bf16(W[k][n]) --------
__global__ __launch_bounds__(256) void k_cvt_w(const float* __restrict__ wq,
        const float* __restrict__ wp, unsigned short* __restrict__ oq,
        unsigned short* __restrict__ op)
{
    int t = blockIdx.x * 256 + threadIdx.x;
    if (t < QKV_N * CH) {
        int n = t / CH, k = t - n * CH;
        oq[t] = f2b(wq[(size_t)k * QKV_N + n]);
    }
    if (t < CH * CH) {
        int n = t / CH, k = t - n * CH;
        op[t] = f2b(wp[(size_t)k * CH + n]);
    }
}

// ---------------- fused bias+mask table: bm[w][h][i][j] ----------------------
__global__ __launch_bounds__(256) void k_bm(const float* __restrict__ btab,
        const float* __restrict__ mask, float* __restrict__ bm)
{
    int t = blockIdx.x * 256 + threadIdx.x;
    if (t >= BM_ELEMS) return;
    int w   = t / (12 * 2401);
    int rem = t - w * 12 * 2401;
    int h   = rem / 2401;
    int ij  = rem - h * 2401;
    int i = ij / 49, j = ij - (ij / 49) * 49;
    int ih = i / 7, iw = i - (i / 7) * 7;
    int jh = j / 7, jw = j - (j / 7) * 7;
    int idx = (ih - jh + 6) * 13 + (iw - jw + 6);
    bm[t] = btab[idx * 12 + h] + mask[(size_t)w * 2401 + ij];
}

// ---------------- x fp32 -> bf16 (vectorized, grid-stride) -------------------
__global__ __launch_bounds__(256) void k_cvt(const float* __restrict__ in,
        unsigned short* __restrict__ outp, int n8)
{
    int stride = gridDim.x * 256;
    for (int i = blockIdx.x * 256 + threadIdx.x; i < n8; i += stride) {
        const float4* p = (const float4*)(in + (size_t)i * 8);
        float4 a = p[0], b = p[1];
        uint4 v;
        v.x = (unsigned)f2b(a.x) | ((unsigned)f2b(a.y) << 16);
        v.y = (unsigned)f2b(a.z) | ((unsigned)f2b(a.w) << 16);
        v.z = (unsigned)f2b(b.x) | ((unsigned)f2b(b.y) << 16);
        v.w = (unsigned)f2b(b.z) | ((unsigned)f2b(b.w) << 16);
        *(uint4*)(outp + (size_t)i * 8) = v;
    }
}

// ---------------- 8-wave GEMM: C[M][ldc] = A @ Bt^T + bias -------------------
// A bf16 row-major [M][lda], Bt bf16 n-major [N][K]. 128x128 tile, BK=32,
// 512 threads (8 waves, 64x32 each -> acc 32 AGPR). 3-buf LDS, depth-2
// prefetch, counted vmcnt (per-wave 2 loads/tile -> vmcnt(4)/2/0).
template<int OUTF32>
__global__ __launch_bounds__(512, 6) void k_gemm(
        const unsigned short* __restrict__ A, int lda,
        const unsigned short* __restrict__ Bt, int K,
        const float* __restrict__ bias,
        unsigned short* __restrict__ Cb, float* __restrict__ Cf, int ldc,
        int M, int ntiles, int mtiles)
{
    __shared__ unsigned short As[3 * 4096];
    __shared__ unsigned short Bs[3 * 4096];
    const int wg = xcd_swizzle(blockIdx.x, mtiles * ntiles);
    const int m0 = (wg / ntiles) * 128;
    const int n0 = (wg % ntiles) * 128;
    const int tid = threadIdx.x;
    const int lane = tid & 63, wv = tid >> 6;
    const int wr = wv >> 2, wc = wv & 3;     // wave tile (64x32) origin
    const int l15 = lane & 15, g = lane >> 4;

    f32x4 acc[4][2];
#pragma unroll
    for (int a = 0; a < 4; ++a)
#pragma unroll
        for (int b = 0; b < 2; ++b) acc[a][b] = (f32x4){0.f, 0.f, 0.f, 0.f};

    // staging: thread covers A row tid>>2 (k-chunk (tid&3)*8), same for B.
    // wave w's 64 lanes -> rows w*16..w*16+15 contiguous 1KB at offset w*512.
    int arow = m0 + (tid >> 2); if (arow > M - 1) arow = M - 1;
    const unsigned short* aP = A + (size_t)arow * lda + (tid & 3) * 8;
    const unsigned short* bP = Bt + (size_t)(n0 + (tid >> 2)) * K + (tid & 3) * 8;
    const int lo = wv * 512;

#define STAGE(kt, buf) do {                                \
        gload16(aP + (kt), &As[(buf) * 4096 + lo]);        \
        gload16(bP + (kt), &Bs[(buf) * 4096 + lo]);        \
    } while (0)

#define COMPUTE(buf) do {                                                       \
        bf16x8 af[4], bfr[2];                                                   \
        _Pragma("unroll")                                                       \
        for (int mt = 0; mt < 4; ++mt)                                          \
            af[mt] = ld8(&As[(buf) * 4096 + (wr * 64 + mt * 16 + l15) * 32 + g * 8]); \
        _Pragma("unroll")                                                       \
        for (int nt = 0; nt < 2; ++nt)                                          \
            bfr[nt] = ld8(&Bs[(buf) * 4096 + (wc * 32 + nt * 16 + l15) * 32 + g * 8]); \
        __builtin_amdgcn_s_setprio(1);                                          \
        _Pragma("unroll")                                                       \
        for (int mt = 0; mt < 4; ++mt)                                          \
            _Pragma("unroll")                                                   \
            for (int nt = 0; nt < 2; ++nt)                                      \
                acc[mt][nt] = __builtin_amdgcn_mfma_f32_16x16x32_bf16(          \
                        af[mt], bfr[nt], acc[mt][nt], 0, 0, 0);                 \
        __builtin_amdgcn_s_setprio(0);                                          \
    } while (0)

    const int nsteps = K >> 5;           // 12 (qkv) or 36 (proj)

    STAGE(0, 0);
    STAGE(32, 1);

    int cur = 0;
    for (int t = 0; t < nsteps - 2; ++t) {
        int pf = cur + 2; if (pf >= 3) pf -= 3;
        STAGE((t + 2) * 32, pf);
        __builtin_amdgcn_sched_barrier(0);
        asm volatile("s_waitcnt vmcnt(4)" ::: "memory");   // tile t's 2 done
        __builtin_amdgcn_sched_barrier(0);
        __builtin_amdgcn_s_barrier();
        __builtin_amdgcn_sched_barrier(0);
        COMPUTE(cur);
        __builtin_amdgcn_sched_barrier(0);
        __builtin_amdgcn_s_barrier();
        __builtin_amdgcn_sched_barrier(0);
        cur = (cur == 2) ? 0 : cur + 1;
    }
    asm volatile("s_waitcnt vmcnt(2)" ::: "memory");
    __builtin_amdgcn_sched_barrier(0);
    __builtin_amdgcn_s_barrier();
    __builtin_amdgcn_sched_barrier(0);
    COMPUTE(cur);
    __builtin_amdgcn_sched_barrier(0);
    __builtin_amdgcn_s_barrier();
    __builtin_amdgcn_sched_barrier(0);
    cur = (cur == 2) ? 0 : cur + 1;
    asm volatile("s_waitcnt vmcnt(0)" ::: "memory");
    __builtin_amdgcn_sched_barrier(0);
    __builtin_amdgcn_s_barrier();
    __builtin_amdgcn_sched_barrier(0);
    COMPUTE(cur);
#undef STAGE
#undef COMPUTE

    // ---- epilogue: scalar stores
#pragma unroll
    for (int mt = 0; mt < 4; ++mt)
#pragma unroll
        for (int nt = 0; nt < 2; ++nt) {
            int col = n0 + wc * 32 + nt * 16 + l15;
            float bb = bias[col];
#pragma unroll
            for (int r = 0; r < 4; ++r) {
                int row = m0 + wr * 64 + mt * 16 + g * 4 + r;
                if (row < M) {
                    if (OUTF32)
                        Cf[(size_t)row * ldc + col] = acc[mt][nt][r] + bb;
                    else
                        Cb[(size_t)row * ldc + col] = f2b(acc[mt][nt][r] + bb);
                }
            }
        }
}

// ---------------- attention: 1 wave per (window, head) -----------------------
// Per-wave LDS: Vt [32][72] + Pw [52][72] = 12,096 B -> 48,384 B/block
// -> 3 blocks/CU. Fused bias+mask from bm table.
__global__ __launch_bounds__(256) void k_attn(unsigned short* __restrict__ qkv,
        const float* __restrict__ bm)
{
    extern __shared__ unsigned short sm[];
    const int tid = threadIdx.x;
    const int lane = tid & 63, wv = tid >> 6;
    const int l15 = lane & 15, g = lane >> 4;
    const int pair = blockIdx.x * 4 + wv;
    const int winloc = pair / 12;
    const int h = pair - winloc * 12;
    const int wimg = winloc & 63;
    const int co = h * 32;
    unsigned short* Vt = sm + wv * 6048;     // [32][72]  V^T
    unsigned short* Pw = Vt + 32 * 72;       // [52][72]  P
    unsigned short* src = qkv + (size_t)winloc * SEQ_N * QKV_N;
    const float* bmh = bm + ((size_t)(wimg * 12 + h)) * 2401;

    for (int t = lane; t < 32 * 16; t += 64) {
        int c = t >> 4, kk = 48 + (t & 15);
        Vt[c * 72 + kk] = 0;
    }
    for (int t = lane; t < 49 * 4; t += 64) {
        int row = t >> 2, cb = (t & 3) * 8;
        const unsigned short* vp = src + (size_t)row * QKV_N + 768 + co + cb;
        ushort4 a = ((const ushort4*)vp)[0];
        ushort4 b = ((const ushort4*)vp)[1];
        Vt[(cb + 0) * 72 + row] = a.x; Vt[(cb + 1) * 72 + row] = a.y;
        Vt[(cb + 2) * 72 + row] = a.z; Vt[(cb + 3) * 72 + row] = a.w;
        Vt[(cb + 4) * 72 + row] = b.x; Vt[(cb + 5) * 72 + row] = b.y;
        Vt[(cb + 6) * 72 + row] = b.z; Vt[(cb + 7) * 72 + row] = b.w;
    }

    bf16x8 qf[4], kf[4];
#pragma unroll
    for (int mt = 0; mt < 4; ++mt) {
        int r = mt * 16 + l15; if (r > 48) r = 48;
        qf[mt] = ld8(src + (size_t)r * QKV_N + co + g * 8);
    }
#pragma unroll
    for (int nt = 0; nt < 4; ++nt) {
        int r = nt * 16 + l15; if (r > 48) r = 48;
        kf[nt] = ld8(src + (size_t)r * QKV_N + CH + co + g * 8);
    }

    f32x4 sa[4][4];
#pragma unroll
    for (int mt = 0; mt < 4; ++mt)
#pragma unroll
        for (int nt = 0; nt < 4; ++nt) sa[mt][nt] = (f32x4){0.f, 0.f, 0.f, 0.f};
#pragma unroll
    for (int mt = 0; mt < 4; ++mt)
#pragma unroll
        for (int nt = 0; nt < 4; ++nt)
            sa[mt][nt] = __builtin_amdgcn_mfma_f32_16x16x32_bf16(
                    qf[mt], kf[nt], sa[mt][nt], 0, 0, 0);

    int jj[4];
#pragma unroll
    for (int nt = 0; nt < 4; ++nt) jj[nt] = nt * 16 + l15;
    const float scale = 0.17677669529663687f;
#pragma unroll
    for (int mt = 0; mt < 4; ++mt) {
#pragma unroll
        for (int r = 0; r < 4; ++r) {
            int i = mt * 16 + g * 4 + r;
            int ic = i < 49 ? i : 48;
            const float* bmrow = bmh + ic * 49;
            float sv[4];
#pragma unroll
            for (int nt = 0; nt < 4; ++nt) {
                float s = sa[mt][nt][r];
                sv[nt] = (jj[nt] < 49) ? (s * scale + bmrow[jj[nt]]) : -1e30f;
            }
            float mx = fmaxf(fmaxf(sv[0], sv[1]), fmaxf(sv[2], sv[3]));
#pragma unroll
            for (int d = 1; d < 16; d <<= 1) mx = fmaxf(mx, __shfl_xor(mx, d));
            float sum = 0.f;
#pragma unroll
            for (int nt = 0; nt < 4; ++nt) { sv[nt] = __expf(sv[nt] - mx); sum += sv[nt]; }
#pragma unroll
            for (int d = 1; d < 16; d <<= 1) sum += __shfl_xor(sum, d);
            float inv = 1.0f / sum;
            if (i < 52) {
#pragma unroll
                for (int nt = 0; nt < 4; ++nt)
                    Pw[i * 72 + nt * 16 + l15] = f2b(sv[nt] * inv);
            }
        }
    }
    __syncthreads();

    f32x4 oa[4][2];
#pragma unroll
    for (int mt = 0; mt < 4; ++mt)
#pragma unroll
        for (int nt = 0; nt < 2; ++nt) oa[mt][nt] = (f32x4){0.f, 0.f, 0.f, 0.f};
#pragma unroll
    for (int ks = 0; ks < 2; ++ks) {
        bf16x8 pf[4];
#pragma unroll
        for (int mt = 0; mt < 4; ++mt) {
            int pr = mt * 16 + l15; if (pr > 51) pr = 51;   // pad rows discarded
            pf[mt] = ld8(Pw + pr * 72 + ks * 32 + g * 8);
        }
#pragma unroll
        for (int nt = 0; nt < 2; ++nt) {
            bf16x8 vf = ld8(Vt + (nt * 16 + l15) * 72 + ks * 32 + g * 8);
#pragma unroll
            for (int mt = 0; mt < 4; ++mt)
                oa[mt][nt] = __builtin_amdgcn_mfma_f32_16x16x32_bf16(
                        pf[mt], vf, oa[mt][nt], 0, 0, 0);
        }
    }

#pragma unroll
    for (int mt = 0; mt < 4; ++mt)
#pragma unroll
        for (int r = 0; r < 4; ++r) {
            int i = mt * 16 + g * 4 + r;
            if (i < 49) {
#pragma unroll
                for (int nt = 0; nt < 2; ++nt)
                    src[(size_t)i * QKV_N + co + nt * 16 + l15] = f2b(oa[mt][nt][r]);
            }
        }
}

extern "C" void kernel_launch(void* const* d_in, const int* in_sizes, int n_in,
                              void* d_out, int out_size, void* d_ws, size_t ws_size,
                              hipStream_t stream) {
    const float* x      = (const float*)d_in[0];
    const float* mask   = (const float*)d_in[1];
    const float* qkv_w  = (const float*)d_in[2];
    const float* qkv_b  = (const float*)d_in[3];
    const float* proj_w = (const float*)d_in[4];
    const float* proj_b = (const float*)d_in[5];
    const float* btab   = (const float*)d_in[6];
    float* out = (float*)d_out;

    unsigned short* wq_bt = (unsigned short*)d_ws;
    unsigned short* wp_bt = wq_bt + QKV_N * CH;
    float*          bm    = (float*)(wp_bt + CH * CH);
    unsigned short* base  = (unsigned short*)(bm + BM_ELEMS);
    const size_t fixed = (size_t)(QKV_N * CH + CH * CH) * 2 + (size_t)BM_ELEMS * 4;
    const size_t unit  = (size_t)UNIT_ROWS * (CH + QKV_N) * 2;
    if (ws_size < fixed + unit) return;
    int upc = (int)((ws_size - fixed) / unit);
    if (upc > 64) upc = 64;
    unsigned short* xb  = base;
    unsigned short* qkv = base + (size_t)upc * UNIT_ROWS * CH;

    const int smem2 = 4 * 6048 * 2;   // 48,384 B -> 3 blocks/CU (attn)
    hipFuncSetAttribute(reinterpret_cast<const void*>(k_attn),
                        hipFuncAttributeMaxDynamicSharedMemorySize, smem2);

    dim3 blk(256);
    k_cvt_w<<<dim3((QKV_N * CH + 255) / 256), blk, 0, stream>>>(qkv_w, proj_w, wq_bt, wp_bt);
    k_bm   <<<dim3((BM_ELEMS + 255) / 256), blk, 0, stream>>>(btab, mask, bm);

    for (int u0 = 0; u0 < 64; u0 += upc) {
        int units = (64 - u0) < upc ? (64 - u0) : upc;
        int m_base = u0 * UNIT_ROWS;
        int Mc = units * UNIT_ROWS;
        int mtiles = (Mc + 127) / 128;
        k_cvt<<<dim3(2048), blk, 0, stream>>>(x + (size_t)m_base * CH, xb, Mc * 48);
        k_gemm<0><<<dim3(mtiles * 9), dim3(512), 0, stream>>>(
                xb, CH, wq_bt, CH, qkv_b, qkv, nullptr, QKV_N, Mc, 9, mtiles);
        k_attn<<<dim3(units * 192), blk, smem2, stream>>>(qkv, bm);
        k_gemm<1><<<dim3(mtiles * 3), dim3(512), 0, stream>>>(
                qkv, QKV_N, wp_bt, CH, proj_b, nullptr, out + (size_t)m_base * CH,
                CH, Mc, 3, mtiles);
    }
}